// Round 12
// baseline (176.457 us; speedup 1.0000x reference)
//
#include <hip/hip_runtime.h>
#include <math.h>

#define T_LEN 100
#define K_LEN 25
#define DLAT 64
#define DHID 128
#define CST 68
#define AST 68

// ---------------------------------------------------------------------------
// buildW: collapse Conv1d(1,64,25,pad=12) + Linear(100,1) into one matrix:
//   h2[n,c] = sum_i x[n,i] * W[c,i] + b2[c]
// ---------------------------------------------------------------------------
__global__ __launch_bounds__(256) void buildW(const float* __restrict__ conv_w,
                                              const float* __restrict__ conv_b,
                                              const float* __restrict__ fc1_w,
                                              const float* __restrict__ fc1_b,
                                              float* __restrict__ W,
                                              float* __restrict__ b2) {
    int idx = blockIdx.x * 256 + threadIdx.x;
    if (idx < 64 * T_LEN) {
        int c = idx / T_LEN, i = idx % T_LEN;
        int t0 = i - 12 > 0 ? i - 12 : 0;
        int t1 = i + 12 < T_LEN - 1 ? i + 12 : T_LEN - 1;
        float acc = 0.f;
        for (int t = t0; t <= t1; ++t)
            acc += fc1_w[t] * conv_w[c * K_LEN + (i - t + 12)];
        W[idx] = acc;
    } else if (idx < 64 * T_LEN + 64) {
        int c = idx - 64 * T_LEN;
        float S = 0.f;
        for (int t = 0; t < T_LEN; ++t) S += fc1_w[t];
        b2[c] = conv_b[c] * S + fc1_b[0];
    }
}

// ---------------------------------------------------------------------------
// phaseCF5: byte-identical body to r11's phaseCF4 (88 us, 44MB spill at the
// allocator's voluntary 64-VGPR choice). ONLY change: occupancy/register
// control via amdgpu_waves_per_eu(4,4) — min=max=4 waves/EU pins the
// allocator's budget at 512/4 = 128 VGPR so it stops squeezing to 64+spill.
// A/B ledger: (512,2)->80 VGPR/no-spill/98us; (512,4)->64 VGPR/44MB/88us.
// Target point: >=80 VGPR, no spill, 16 waves/CU.
// ---------------------------------------------------------------------------
__global__ void
__attribute__((amdgpu_flat_work_group_size(512, 512), amdgpu_waves_per_eu(4, 4)))
phaseCF5(const float* __restrict__ x,
         const int* __restrict__ ei,
         const float* __restrict__ Wm,
         const float* __restrict__ b2,
         const float* __restrict__ rel_w,
         const float* __restrict__ rel_b,
         const float* __restrict__ root_w,
         float* __restrict__ Sg,
         float* __restrict__ Qg,
         int E, int G) {
    __shared__ float h2s[64 * CST];
    __shared__ float aggs[64 * CST];
    __shared__ unsigned Asu[64 * AST];

    int tid = threadIdx.x;
    int bid = blockIdx.x;
    int lane = tid & 63;
    int w = __builtin_amdgcn_readfirstlane(tid >> 6);  // 0..7, uniform

    // bijective XCD swizzle (m204): graphs sharing edge cachelines land on
    // the same XCD so the stride-G edge reads are L2 hits.
    int q = G >> 3, r = G & 7;
    int xc = bid & 7, o = bid >> 3;
    int g = (xc < r ? xc * (q + 1) : r * (q + 1) + (xc - r) * q) + o;

    int epg = E / G;
    bool fast = (epg == 2048);

    // 0. issue strided edge loads EARLY; the vmcnt wait lands after the
    // encoder loop, so HBM/L2 latency hides under phase 1 compute.
    int es0 = 0, es1 = 0, es2 = 0, es3 = 0;
    int ed0 = 0, ed1 = 0, ed2 = 0, ed3 = 0;
    if (fast) {
        int e0 = g + tid * G;
        int st = 512 * G;
        es0 = ei[e0];            ed0 = ei[E + e0];
        es1 = ei[e0 + st];       ed1 = ei[E + e0 + st];
        es2 = ei[e0 + 2 * st];   ed2 = ei[E + e0 + 2 * st];
        es3 = ei[e0 + 3 * st];   ed3 = ei[E + e0 + 3 * st];
    }

    // zero adjacency counters
    for (int idx = tid; idx < 64 * AST; idx += 512) Asu[idx] = 0u;

    // 1. encoder: h2s[lane][8w..8w+8)
    {
        const float4* __restrict__ xp =
            (const float4*)(x + (size_t)(g * 64 + lane) * T_LEN);
        const float* __restrict__ Wb = Wm + w * 8 * T_LEN;  // uniform
        float acc[8];
#pragma unroll
        for (int c = 0; c < 8; ++c) acc[c] = 0.f;
#pragma unroll
        for (int tq = 0; tq < T_LEN / 4; ++tq) {
            float4 xv = xp[tq];
#pragma unroll
            for (int c = 0; c < 8; ++c) {
                const float* wr = Wb + c * T_LEN + tq * 4;  // uniform -> s_load
                acc[c] += xv.x * wr[0] + xv.y * wr[1] + xv.z * wr[2] + xv.w * wr[3];
            }
        }
        float4 o0, o1;
        o0.x = acc[0] + b2[w * 8 + 0];
        o0.y = acc[1] + b2[w * 8 + 1];
        o0.z = acc[2] + b2[w * 8 + 2];
        o0.w = acc[3] + b2[w * 8 + 3];
        o1.x = acc[4] + b2[w * 8 + 4];
        o1.y = acc[5] + b2[w * 8 + 5];
        o1.z = acc[6] + b2[w * 8 + 6];
        o1.w = acc[7] + b2[w * 8 + 7];
        *(float4*)&h2s[lane * CST + w * 8] = o0;
        *(float4*)&h2s[lane * CST + w * 8 + 4] = o1;
    }
    __syncthreads();

    // 2. edge counting via LDS atomics
    if (fast) {
        atomicAdd(&Asu[(ed0 & 63) * AST + (es0 & 63)], 1u);
        atomicAdd(&Asu[(ed1 & 63) * AST + (es1 & 63)], 1u);
        atomicAdd(&Asu[(ed2 & 63) * AST + (es2 & 63)], 1u);
        atomicAdd(&Asu[(ed3 & 63) * AST + (es3 & 63)], 1u);
    } else {
        for (int k = tid; k < epg; k += 512) {
            int e = g + k * G;
            atomicAdd(&Asu[(ei[E + e] & 63) * AST + (ei[e] & 63)], 1u);
        }
    }
    __syncthreads();

    // 3. agg = A @ h2 (convert counts inline). thread owns (n, n+32) x 4 ch.
    {
        int c4 = (tid & 15) * 4;
        int n0 = tid >> 4;  // 0..31
#pragma unroll
        for (int i = 0; i < 2; ++i) {
            int n = n0 + 32 * i;
            float4 a4 = {0.f, 0.f, 0.f, 0.f};
#pragma unroll 4
            for (int s4 = 0; s4 < 16; ++s4) {
                uint4 au = *(const uint4*)&Asu[n * AST + 4 * s4];
                float a0 = (float)au.x, a1 = (float)au.y;
                float a2 = (float)au.z, a3 = (float)au.w;
                float4 h0 = *(const float4*)&h2s[(4 * s4 + 0) * CST + c4];
                float4 h1 = *(const float4*)&h2s[(4 * s4 + 1) * CST + c4];
                float4 h2v = *(const float4*)&h2s[(4 * s4 + 2) * CST + c4];
                float4 h3 = *(const float4*)&h2s[(4 * s4 + 3) * CST + c4];
                a4.x += a0 * h0.x + a1 * h1.x + a2 * h2v.x + a3 * h3.x;
                a4.y += a0 * h0.y + a1 * h1.y + a2 * h2v.y + a3 * h3.y;
                a4.z += a0 * h0.z + a1 * h1.z + a2 * h2v.z + a3 * h3.z;
                a4.w += a0 * h0.w + a1 * h1.w + a2 * h2v.w + a3 * h3.w;
            }
            *(float4*)&aggs[n * CST + c4] = a4;
        }
    }
    __syncthreads();

    // 4. part2: wave w owns j in [16w,16w+16), jb halves of 8 j's,
    //    channel chunks of 8 floats (16 live z floats + acc[8]).
#pragma unroll
    for (int jb = 0; jb < 2; ++jb) {
        float acc[8];
#pragma unroll
        for (int ji = 0; ji < 8; ++ji) acc[ji] = 0.f;

#pragma unroll
        for (int mc = 0; mc < 8; ++mc) {
            float4 za0 = *(const float4*)&aggs[lane * CST + mc * 8];
            float4 za1 = *(const float4*)&aggs[lane * CST + mc * 8 + 4];
            float4 zh0 = *(const float4*)&h2s[lane * CST + mc * 8];
            float4 zh1 = *(const float4*)&h2s[lane * CST + mc * 8 + 4];
#pragma unroll
            for (int ji = 0; ji < 8; ++ji) {
                int j = w * 16 + jb * 8 + ji;  // uniform
                const float* rp = rel_w + (size_t)j * DLAT + mc * 8;   // 32B run
                const float* op = root_w + (size_t)j * DLAT + mc * 8;
                float a = acc[ji];
                a += za0.x * rp[0] + za0.y * rp[1] + za0.z * rp[2] + za0.w * rp[3];
                a += za1.x * rp[4] + za1.y * rp[5] + za1.z * rp[6] + za1.w * rp[7];
                a += zh0.x * op[0] + zh0.y * op[1] + zh0.z * op[2] + zh0.w * op[3];
                a += zh1.x * op[4] + zh1.y * op[5] + zh1.z * op[6] + zh1.w * op[7];
                acc[ji] = a;
            }
        }

#pragma unroll
        for (int ji = 0; ji < 8; ++ji) {
            int j = w * 16 + jb * 8 + ji;
            float outv = acc[ji] + rel_b[j];
            float sq = outv * outv;
#pragma unroll
            for (int off = 32; off; off >>= 1) {
                outv += __shfl_xor(outv, off);
                sq += __shfl_xor(sq, off);
            }
            if (lane == 0) {
                Sg[g * DHID + j] = outv;
                Qg[g * DHID + j] = sq;
            }
        }
    }
}

// ---------------------------------------------------------------------------
// Phase D: BN stats per channel -> a[j], b[j] (scale/shift)
// ---------------------------------------------------------------------------
__global__ __launch_bounds__(256) void phaseD2(const float* __restrict__ Sg,
                                               const float* __restrict__ Qg,
                                               const float* __restrict__ gamma,
                                               const float* __restrict__ beta,
                                               float* __restrict__ ab,
                                               int G, int N) {
    int j = blockIdx.x;
    int t = threadIdx.x;
    float s = 0.f, q = 0.f;
    for (int g = t; g < G; g += 256) {
        s += Sg[g * DHID + j];
        q += Qg[g * DHID + j];
    }
#pragma unroll
    for (int off = 32; off; off >>= 1) {
        s += __shfl_xor(s, off);
        q += __shfl_xor(q, off);
    }
    __shared__ float rs[4], rq[4];
    int wv = t >> 6;
    if ((t & 63) == 0) { rs[wv] = s; rq[wv] = q; }
    __syncthreads();
    if (t == 0) {
        s = rs[0] + rs[1] + rs[2] + rs[3];
        q = rq[0] + rq[1] + rq[2] + rq[3];
        float inv_n = 1.f / (float)N;
        float mean = s * inv_n;
        float var = q * inv_n - mean * mean;
        float a = rsqrtf(var + 1e-5f) * gamma[j];
        float b = beta[j] - mean * a;
        ab[j] = a;
        ab[DHID + j] = b;
    }
}

// ---------------------------------------------------------------------------
// Phase E: pooled = (a^2 Q + 2ab S)/64 + b^2 ; log(clamp) ; fc2 ; sigmoid
// ---------------------------------------------------------------------------
__global__ __launch_bounds__(128) void phaseE(const float* __restrict__ Sg,
                                              const float* __restrict__ Qg,
                                              const float* __restrict__ ab,
                                              const float* __restrict__ fc2_w,
                                              const float* __restrict__ fc2_b,
                                              float* __restrict__ y) {
    int g = blockIdx.x;
    int j = threadIdx.x;
    __shared__ float ps[DHID];
    float a = ab[j], b = ab[DHID + j];
    float S = Sg[g * DHID + j], Q = Qg[g * DHID + j];
    float pooled = (a * a * Q + 2.f * a * b * S) * (1.f / 64.f) + b * b;
    pooled = fmaxf(pooled, 1e-6f);
    ps[j] = logf(pooled);
    __syncthreads();
    if (j < 3) {
        float acc = fc2_b[j];
        for (int c = 0; c < DHID; ++c) acc += ps[c] * fc2_w[j * DHID + c];
        y[g * 3 + j] = 1.f / (1.f + expf(-acc));
    }
}

// ---------------------------------------------------------------------------
extern "C" void kernel_launch(void* const* d_in, const int* in_sizes, int n_in,
                              void* d_out, int out_size, void* d_ws, size_t ws_size,
                              hipStream_t stream) {
    const float* x      = (const float*)d_in[0];
    const int*   ei     = (const int*)d_in[1];
    const float* conv_w = (const float*)d_in[3];
    const float* conv_b = (const float*)d_in[4];
    const float* fc1_w  = (const float*)d_in[5];
    const float* fc1_b  = (const float*)d_in[6];
    const float* rel_w  = (const float*)d_in[7];
    const float* rel_b  = (const float*)d_in[8];
    const float* root_w = (const float*)d_in[9];
    const float* gamma  = (const float*)d_in[10];
    const float* beta   = (const float*)d_in[11];
    const float* fc2_w  = (const float*)d_in[12];
    const float* fc2_b  = (const float*)d_in[13];
    float* y = (float*)d_out;

    int N = in_sizes[2];       // 32768
    int E = in_sizes[1] / 2;   // 1048576
    int G = N / 64;            // 512

    float* Sg = (float*)d_ws;                  // G*128
    float* Qg = Sg + (size_t)G * DHID;         // G*128
    float* ab = Qg + (size_t)G * DHID;         // 2*128
    float* Wm = ab + 2 * DHID;                 // 64*100
    float* b2 = Wm + 64 * T_LEN;               // 64

    buildW<<<26, 256, 0, stream>>>(conv_w, conv_b, fc1_w, fc1_b, Wm, b2);
    phaseCF5<<<G, 512, 0, stream>>>(x, ei, Wm, b2, rel_w, rel_b, root_w,
                                    Sg, Qg, E, G);
    phaseD2<<<DHID, 256, 0, stream>>>(Sg, Qg, gamma, beta, ab, G, N);
    phaseE<<<G, DHID, 0, stream>>>(Sg, Qg, ab, fc2_w, fc2_b, y);
}

// Round 13
// 175.809 us; speedup vs baseline: 1.0037x; 1.0037x over previous
//
#include <hip/hip_runtime.h>
#include <math.h>

#define T_LEN 100
#define K_LEN 25
#define DLAT 64
#define DHID 128
#define CST 68
#define AST 68

// ---------------------------------------------------------------------------
// buildW: collapse Conv1d(1,64,25,pad=12) + Linear(100,1) into one matrix:
//   h2[n,c] = sum_i x[n,i] * W[c,i] + b2[c]
// ---------------------------------------------------------------------------
__global__ __launch_bounds__(256) void buildW(const float* __restrict__ conv_w,
                                              const float* __restrict__ conv_b,
                                              const float* __restrict__ fc1_w,
                                              const float* __restrict__ fc1_b,
                                              float* __restrict__ W,
                                              float* __restrict__ b2) {
    int idx = blockIdx.x * 256 + threadIdx.x;
    if (idx < 64 * T_LEN) {
        int c = idx / T_LEN, i = idx % T_LEN;
        int t0 = i - 12 > 0 ? i - 12 : 0;
        int t1 = i + 12 < T_LEN - 1 ? i + 12 : T_LEN - 1;
        float acc = 0.f;
        for (int t = t0; t <= t1; ++t)
            acc += fc1_w[t] * conv_w[c * K_LEN + (i - t + 12)];
        W[idx] = acc;
    } else if (idx < 64 * T_LEN + 64) {
        int c = idx - 64 * T_LEN;
        float S = 0.f;
        for (int t = 0; t < T_LEN; ++t) S += fc1_w[t];
        b2[c] = conv_b[c] * S + fc1_b[0];
    }
}

// ---------------------------------------------------------------------------
// phaseCF6: r11's phaseCF4 with ONE change: the encoder tq loop is ROLLED.
// Spill-source attribution (r9 vs r2/r11/r12 A/B at same allocation class):
//   rolled encoder (r9)   -> VGPR 56, WRITE 558 KB (no spill)
//   unrolled encoder      -> VGPR 64, WRITE 44 MB  (spill)
// The full unroll hoists ~25 float4 x-loads (~100 VGPRs in flight) over the
// 64-VGPR budget the (512,4) allocator picks. Rolling it keeps 2-3 loads in
// flight. Everything else is byte-identical to the 87-88 us kernel.
// ---------------------------------------------------------------------------
__global__ __launch_bounds__(512, 4) void phaseCF6(const float* __restrict__ x,
                                                   const int* __restrict__ ei,
                                                   const float* __restrict__ Wm,
                                                   const float* __restrict__ b2,
                                                   const float* __restrict__ rel_w,
                                                   const float* __restrict__ rel_b,
                                                   const float* __restrict__ root_w,
                                                   float* __restrict__ Sg,
                                                   float* __restrict__ Qg,
                                                   int E, int G) {
    __shared__ float h2s[64 * CST];
    __shared__ float aggs[64 * CST];
    __shared__ unsigned Asu[64 * AST];

    int tid = threadIdx.x;
    int bid = blockIdx.x;
    int lane = tid & 63;
    int w = __builtin_amdgcn_readfirstlane(tid >> 6);  // 0..7, uniform

    // bijective XCD swizzle (m204): graphs sharing edge cachelines land on
    // the same XCD so the stride-G edge reads are L2 hits.
    int q = G >> 3, r = G & 7;
    int xc = bid & 7, o = bid >> 3;
    int g = (xc < r ? xc * (q + 1) : r * (q + 1) + (xc - r) * q) + o;

    int epg = E / G;
    bool fast = (epg == 2048);

    // 0. issue strided edge loads EARLY; the vmcnt wait lands after the
    // encoder loop, so HBM/L2 latency hides under phase 1 compute.
    int es0 = 0, es1 = 0, es2 = 0, es3 = 0;
    int ed0 = 0, ed1 = 0, ed2 = 0, ed3 = 0;
    if (fast) {
        int e0 = g + tid * G;
        int st = 512 * G;
        es0 = ei[e0];            ed0 = ei[E + e0];
        es1 = ei[e0 + st];       ed1 = ei[E + e0 + st];
        es2 = ei[e0 + 2 * st];   ed2 = ei[E + e0 + 2 * st];
        es3 = ei[e0 + 3 * st];   ed3 = ei[E + e0 + 3 * st];
    }

    // zero adjacency counters
    for (int idx = tid; idx < 64 * AST; idx += 512) Asu[idx] = 0u;

    // 1. encoder: h2s[lane][8w..8w+8)  -- tq loop ROLLED (the one change)
    {
        const float4* __restrict__ xp =
            (const float4*)(x + (size_t)(g * 64 + lane) * T_LEN);
        const float* __restrict__ Wb = Wm + w * 8 * T_LEN;  // uniform
        float acc[8];
#pragma unroll
        for (int c = 0; c < 8; ++c) acc[c] = 0.f;
        for (int tq = 0; tq < T_LEN / 4; ++tq) {   // rolled: no unroll pragma
            float4 xv = xp[tq];
#pragma unroll
            for (int c = 0; c < 8; ++c) {
                const float* wr = Wb + c * T_LEN + tq * 4;  // uniform -> s_load
                acc[c] += xv.x * wr[0] + xv.y * wr[1] + xv.z * wr[2] + xv.w * wr[3];
            }
        }
        float4 o0, o1;
        o0.x = acc[0] + b2[w * 8 + 0];
        o0.y = acc[1] + b2[w * 8 + 1];
        o0.z = acc[2] + b2[w * 8 + 2];
        o0.w = acc[3] + b2[w * 8 + 3];
        o1.x = acc[4] + b2[w * 8 + 4];
        o1.y = acc[5] + b2[w * 8 + 5];
        o1.z = acc[6] + b2[w * 8 + 6];
        o1.w = acc[7] + b2[w * 8 + 7];
        *(float4*)&h2s[lane * CST + w * 8] = o0;
        *(float4*)&h2s[lane * CST + w * 8 + 4] = o1;
    }
    __syncthreads();

    // 2. edge counting via LDS atomics
    if (fast) {
        atomicAdd(&Asu[(ed0 & 63) * AST + (es0 & 63)], 1u);
        atomicAdd(&Asu[(ed1 & 63) * AST + (es1 & 63)], 1u);
        atomicAdd(&Asu[(ed2 & 63) * AST + (es2 & 63)], 1u);
        atomicAdd(&Asu[(ed3 & 63) * AST + (es3 & 63)], 1u);
    } else {
        for (int k = tid; k < epg; k += 512) {
            int e = g + k * G;
            atomicAdd(&Asu[(ei[E + e] & 63) * AST + (ei[e] & 63)], 1u);
        }
    }
    __syncthreads();

    // 3. agg = A @ h2 (convert counts inline). thread owns (n, n+32) x 4 ch.
    {
        int c4 = (tid & 15) * 4;
        int n0 = tid >> 4;  // 0..31
#pragma unroll
        for (int i = 0; i < 2; ++i) {
            int n = n0 + 32 * i;
            float4 a4 = {0.f, 0.f, 0.f, 0.f};
#pragma unroll 4
            for (int s4 = 0; s4 < 16; ++s4) {
                uint4 au = *(const uint4*)&Asu[n * AST + 4 * s4];
                float a0 = (float)au.x, a1 = (float)au.y;
                float a2 = (float)au.z, a3 = (float)au.w;
                float4 h0 = *(const float4*)&h2s[(4 * s4 + 0) * CST + c4];
                float4 h1 = *(const float4*)&h2s[(4 * s4 + 1) * CST + c4];
                float4 h2v = *(const float4*)&h2s[(4 * s4 + 2) * CST + c4];
                float4 h3 = *(const float4*)&h2s[(4 * s4 + 3) * CST + c4];
                a4.x += a0 * h0.x + a1 * h1.x + a2 * h2v.x + a3 * h3.x;
                a4.y += a0 * h0.y + a1 * h1.y + a2 * h2v.y + a3 * h3.y;
                a4.z += a0 * h0.z + a1 * h1.z + a2 * h2v.z + a3 * h3.z;
                a4.w += a0 * h0.w + a1 * h1.w + a2 * h2v.w + a3 * h3.w;
            }
            *(float4*)&aggs[n * CST + c4] = a4;
        }
    }
    __syncthreads();

    // 4. part2: wave w owns j in [16w,16w+16), jb halves of 8 j's,
    //    channel chunks of 8 floats (16 live z floats + acc[8]).
#pragma unroll
    for (int jb = 0; jb < 2; ++jb) {
        float acc[8];
#pragma unroll
        for (int ji = 0; ji < 8; ++ji) acc[ji] = 0.f;

#pragma unroll
        for (int mc = 0; mc < 8; ++mc) {
            float4 za0 = *(const float4*)&aggs[lane * CST + mc * 8];
            float4 za1 = *(const float4*)&aggs[lane * CST + mc * 8 + 4];
            float4 zh0 = *(const float4*)&h2s[lane * CST + mc * 8];
            float4 zh1 = *(const float4*)&h2s[lane * CST + mc * 8 + 4];
#pragma unroll
            for (int ji = 0; ji < 8; ++ji) {
                int j = w * 16 + jb * 8 + ji;  // uniform
                const float* rp = rel_w + (size_t)j * DLAT + mc * 8;   // 32B run
                const float* op = root_w + (size_t)j * DLAT + mc * 8;
                float a = acc[ji];
                a += za0.x * rp[0] + za0.y * rp[1] + za0.z * rp[2] + za0.w * rp[3];
                a += za1.x * rp[4] + za1.y * rp[5] + za1.z * rp[6] + za1.w * rp[7];
                a += zh0.x * op[0] + zh0.y * op[1] + zh0.z * op[2] + zh0.w * op[3];
                a += zh1.x * op[4] + zh1.y * op[5] + zh1.z * op[6] + zh1.w * op[7];
                acc[ji] = a;
            }
        }

#pragma unroll
        for (int ji = 0; ji < 8; ++ji) {
            int j = w * 16 + jb * 8 + ji;
            float outv = acc[ji] + rel_b[j];
            float sq = outv * outv;
#pragma unroll
            for (int off = 32; off; off >>= 1) {
                outv += __shfl_xor(outv, off);
                sq += __shfl_xor(sq, off);
            }
            if (lane == 0) {
                Sg[g * DHID + j] = outv;
                Qg[g * DHID + j] = sq;
            }
        }
    }
}

// ---------------------------------------------------------------------------
// Phase D: BN stats per channel -> a[j], b[j] (scale/shift)
// ---------------------------------------------------------------------------
__global__ __launch_bounds__(256) void phaseD2(const float* __restrict__ Sg,
                                               const float* __restrict__ Qg,
                                               const float* __restrict__ gamma,
                                               const float* __restrict__ beta,
                                               float* __restrict__ ab,
                                               int G, int N) {
    int j = blockIdx.x;
    int t = threadIdx.x;
    float s = 0.f, q = 0.f;
    for (int g = t; g < G; g += 256) {
        s += Sg[g * DHID + j];
        q += Qg[g * DHID + j];
    }
#pragma unroll
    for (int off = 32; off; off >>= 1) {
        s += __shfl_xor(s, off);
        q += __shfl_xor(q, off);
    }
    __shared__ float rs[4], rq[4];
    int wv = t >> 6;
    if ((t & 63) == 0) { rs[wv] = s; rq[wv] = q; }
    __syncthreads();
    if (t == 0) {
        s = rs[0] + rs[1] + rs[2] + rs[3];
        q = rq[0] + rq[1] + rq[2] + rq[3];
        float inv_n = 1.f / (float)N;
        float mean = s * inv_n;
        float var = q * inv_n - mean * mean;
        float a = rsqrtf(var + 1e-5f) * gamma[j];
        float b = beta[j] - mean * a;
        ab[j] = a;
        ab[DHID + j] = b;
    }
}

// ---------------------------------------------------------------------------
// Phase E: pooled = (a^2 Q + 2ab S)/64 + b^2 ; log(clamp) ; fc2 ; sigmoid
// ---------------------------------------------------------------------------
__global__ __launch_bounds__(128) void phaseE(const float* __restrict__ Sg,
                                              const float* __restrict__ Qg,
                                              const float* __restrict__ ab,
                                              const float* __restrict__ fc2_w,
                                              const float* __restrict__ fc2_b,
                                              float* __restrict__ y) {
    int g = blockIdx.x;
    int j = threadIdx.x;
    __shared__ float ps[DHID];
    float a = ab[j], b = ab[DHID + j];
    float S = Sg[g * DHID + j], Q = Qg[g * DHID + j];
    float pooled = (a * a * Q + 2.f * a * b * S) * (1.f / 64.f) + b * b;
    pooled = fmaxf(pooled, 1e-6f);
    ps[j] = logf(pooled);
    __syncthreads();
    if (j < 3) {
        float acc = fc2_b[j];
        for (int c = 0; c < DHID; ++c) acc += ps[c] * fc2_w[j * DHID + c];
        y[g * 3 + j] = 1.f / (1.f + expf(-acc));
    }
}

// ---------------------------------------------------------------------------
extern "C" void kernel_launch(void* const* d_in, const int* in_sizes, int n_in,
                              void* d_out, int out_size, void* d_ws, size_t ws_size,
                              hipStream_t stream) {
    const float* x      = (const float*)d_in[0];
    const int*   ei     = (const int*)d_in[1];
    const float* conv_w = (const float*)d_in[3];
    const float* conv_b = (const float*)d_in[4];
    const float* fc1_w  = (const float*)d_in[5];
    const float* fc1_b  = (const float*)d_in[6];
    const float* rel_w  = (const float*)d_in[7];
    const float* rel_b  = (const float*)d_in[8];
    const float* root_w = (const float*)d_in[9];
    const float* gamma  = (const float*)d_in[10];
    const float* beta   = (const float*)d_in[11];
    const float* fc2_w  = (const float*)d_in[12];
    const float* fc2_b  = (const float*)d_in[13];
    float* y = (float*)d_out;

    int N = in_sizes[2];       // 32768
    int E = in_sizes[1] / 2;   // 1048576
    int G = N / 64;            // 512

    float* Sg = (float*)d_ws;                  // G*128
    float* Qg = Sg + (size_t)G * DHID;         // G*128
    float* ab = Qg + (size_t)G * DHID;         // 2*128
    float* Wm = ab + 2 * DHID;                 // 64*100
    float* b2 = Wm + 64 * T_LEN;               // 64

    buildW<<<26, 256, 0, stream>>>(conv_w, conv_b, fc1_w, fc1_b, Wm, b2);
    phaseCF6<<<G, 512, 0, stream>>>(x, ei, Wm, b2, rel_w, rel_b, root_w,
                                    Sg, Qg, E, G);
    phaseD2<<<DHID, 256, 0, stream>>>(Sg, Qg, gamma, beta, ab, G, N);
    phaseE<<<G, DHID, 0, stream>>>(Sg, Qg, ab, fc2_w, fc2_b, y);
}